// Round 2
// baseline (361.464 us; speedup 1.0000x reference)
//
#include <hip/hip_runtime.h>

typedef __attribute__((ext_vector_type(8))) short s16x8;
typedef __attribute__((ext_vector_type(4))) float f32x4;
typedef unsigned short u16;
typedef unsigned int u32;

constexpr int NN = 50000;
constexpr int NE = 600000;

__device__ inline u16 f2b(float x) {
    u32 u = __float_as_uint(x);
    u = (u + 0x7FFFu + ((u >> 16) & 1u)) >> 16;   // RNE
    return (u16)u;
}
__device__ inline float b2f(u16 s) { return __uint_as_float(((u32)s) << 16); }

__device__ inline s16x8 pack8(float4 a, float4 b) {
    s16x8 r;
    r[0] = (short)f2b(a.x); r[1] = (short)f2b(a.y);
    r[2] = (short)f2b(a.z); r[3] = (short)f2b(a.w);
    r[4] = (short)f2b(b.x); r[5] = (short)f2b(b.y);
    r[6] = (short)f2b(b.z); r[7] = (short)f2b(b.w);
    return r;
}

// ---------------- misc small kernels ----------------

__global__ void k_zero(int* __restrict__ p, int n) {
    int i = blockIdx.x * 256 + threadIdx.x;
    if (i < n) p[i] = 0;
}

// WTin[c][k], k<768: (fc2_w @ relu_w_bot)^T ; 768..783: (fc1_w @ relu_w_top)^T ; 784..799: 0
__global__ void k_win(const float* __restrict__ fc1w, const float* __restrict__ fc2w,
                      const float* __restrict__ reluw, u16* __restrict__ WTin) {
    int c = threadIdx.x;         // 0..127 output col
    int k = blockIdx.x;          // 0..799
    float s = 0.f;
    if (k < 768) {
        for (int j = 0; j < 128; ++j) s += fc2w[k * 128 + j] * reluw[(128 + j) * 128 + c];
    } else if (k < 784) {
        int kk = k - 768;
        for (int j = 0; j < 128; ++j) s += fc1w[kk * 128 + j] * reluw[j * 128 + c];
    }
    WTin[c * 800 + k] = f2b(s);
}

__global__ void k_bcomb(const float* __restrict__ fc1b, const float* __restrict__ fc2b,
                        const float* __restrict__ relub, const float* __restrict__ reluw,
                        float* __restrict__ bcomb) {
    int c = threadIdx.x;
    float s = relub[c];
    for (int j = 0; j < 128; ++j) {
        s += fc1b[j] * reluw[j * 128 + c];
        s += fc2b[j] * reluw[(128 + j) * 128 + c];
    }
    bcomb[c] = s;
}

// WT[c][s] = stacked [wrel(3x128x128); wroot(128x128)] transposed, bf16
__global__ void k_wrg(const float* __restrict__ wrel, const float* __restrict__ wroot,
                      u16* __restrict__ WT) {
    int c = threadIdx.x;   // e index
    int s = blockIdx.x;    // 0..511 stacked row
    float v = (s < 384) ? wrel[(size_t)s * 128 + c] : wroot[(size_t)(s - 384) * 128 + c];
    WT[c * 512 + s] = f2b(v);
}

// ---------------- CSR build ----------------

__global__ void k_hist(const int* __restrict__ ei, const int* __restrict__ et,
                       int* __restrict__ deg_node, int* __restrict__ deg_rel) {
    int e = blockIdx.x * 256 + threadIdx.x;
    if (e >= NE) return;
    int dst = ei[NE + e];
    int r = et[e];
    atomicAdd(&deg_node[dst], 1);
    atomicAdd(&deg_rel[r * NN + dst], 1);
}

__global__ void k_alloc(const int* __restrict__ deg_node, int* __restrict__ baseoff,
                        int* __restrict__ counter) {
    int i = blockIdx.x * 256 + threadIdx.x;
    int lane = threadIdx.x & 63;
    int d = (i < NN) ? deg_node[i] : 0;
    int scan = d;
    for (int off = 1; off < 64; off <<= 1) {
        int t = __shfl_up(scan, off, 64);
        if (lane >= off) scan += t;
    }
    int total = __shfl(scan, 63, 64);
    int wbase = 0;
    if (lane == 63) wbase = atomicAdd(counter, total);
    wbase = __shfl(wbase, 63, 64);
    if (i < NN) baseoff[i] = wbase + scan - d;  // exclusive prefix within wave + global base
}

__global__ void k_norm(const int* __restrict__ deg_rel, float* __restrict__ normf) {
    int i = blockIdx.x * 256 + threadIdx.x;
    if (i < 3 * NN) normf[i] = 1.0f / (float)max(deg_rel[i], 1);
}

__global__ void k_fill(const int* __restrict__ ei, const int* __restrict__ et,
                       const int* __restrict__ baseoff, int* __restrict__ cursor,
                       int* __restrict__ elist) {
    int e = blockIdx.x * 256 + threadIdx.x;
    if (e >= NE) return;
    int dst = ei[NE + e];
    int src = ei[e];
    int r = et[e];
    int pos = atomicAdd(&cursor[dst], 1);
    elist[baseoff[dst] + pos] = src | (r << 20);
}

// ---------------- aggregation (gather over CSR) ----------------

__global__ __launch_bounds__(128) void k_agg(const u16* __restrict__ x, u16* __restrict__ A,
                                             const int* __restrict__ elist,
                                             const int* __restrict__ baseoff,
                                             const int* __restrict__ deg_node,
                                             const float* __restrict__ normf) {
    int n = blockIdx.x;
    int f = threadIdx.x;  // feature 0..127
    float a0 = 0.f, a1 = 0.f, a2 = 0.f;
    int nb = deg_node[n];
    int b0 = baseoff[n];
    for (int i = 0; i < nb; ++i) {
        int p = elist[b0 + i];
        int src = p & 0xFFFFF;
        int r = p >> 20;
        float v = b2f(x[(size_t)src * 128 + f]);
        if (r == 0) a0 += v;
        else if (r == 1) a1 += v;
        else a2 += v;
    }
    A[(size_t)n * 384 + f]       = f2b(a0 * normf[n]);
    A[(size_t)n * 384 + 128 + f] = f2b(a1 * normf[NN + n]);
    A[(size_t)n * 384 + 256 + f] = f2b(a2 * normf[2 * NN + n]);
}

// ---------------- GEMM: [N, K1T*32 (+K2T*32)] x WT^T -> [N,128] bf16 ----------------
// A row = concat(A1 row (K1T tiles), A2 row (K2T tiles, first A2V cols valid, rest 0))
// WT is [128][ldwt] bf16 row-major (transposed weights). Epilogue: +bias, optional leaky-relu.

template <typename TA, int K1T, int K2T, int A2V, bool LRELU>
__global__ __launch_bounds__(256) void k_gemm(const TA* __restrict__ A1, int lda1,
                                              const TA* __restrict__ A2, int lda2,
                                              const u16* __restrict__ WT, int ldwt,
                                              const float* __restrict__ bias,
                                              u16* __restrict__ out, int N) {
    __shared__ u16 As[128][40];  // +8 pad -> 80B stride, 2-way bank alias only
    __shared__ u16 Bs[128][40];  // Bs[col][k]
    const int tid = threadIdx.x;
    const int m0 = blockIdx.x * 128;
    const int sr = tid >> 1;           // staging row / weight col 0..127
    const int kcol = (tid & 1) * 16;   // staging k-offset
    const int w = tid >> 6, lane = tid & 63;
    const int wr = w >> 1, wc = w & 1, lq = lane >> 4, lr = lane & 15;
    constexpr int KT = K1T + K2T;

    f32x4 acc[4][4] = {};

    for (int kt = 0; kt < KT; ++kt) {
        // ---- stage A tile [128][32] (convert fp32->bf16 if needed) ----
        s16x8 alo = {}, ahi = {};
        const int grow = m0 + sr;
        if (grow < N) {
            const TA* p = nullptr;
            if (kt < K1T) {
                p = A1 + (size_t)grow * lda1 + kt * 32 + kcol;
            } else {
                int k2 = (kt - K1T) * 32 + kcol;
                if (k2 < A2V) p = A2 + (size_t)grow * lda2 + k2;
            }
            if (p) {
                if constexpr (sizeof(TA) == 4) {
                    const float4* q = (const float4*)p;
                    float4 f0 = q[0], f1 = q[1], f2 = q[2], f3 = q[3];
                    alo = pack8(f0, f1);
                    ahi = pack8(f2, f3);
                } else {
                    const s16x8* q = (const s16x8*)p;
                    alo = q[0];
                    ahi = q[1];
                }
            }
        }
        // ---- stage B tile: Bs[col][k] from WT[col][kt*32 + k] ----
        const u16* bp = WT + (size_t)sr * ldwt + kt * 32 + kcol;
        s16x8 blo = ((const s16x8*)bp)[0];
        s16x8 bhi = ((const s16x8*)bp)[1];

        *(s16x8*)&As[sr][kcol] = alo;
        *(s16x8*)&As[sr][kcol + 8] = ahi;
        *(s16x8*)&Bs[sr][kcol] = blo;
        *(s16x8*)&Bs[sr][kcol + 8] = bhi;
        __syncthreads();

        s16x8 af[4], bfv[4];
#pragma unroll
        for (int i = 0; i < 4; ++i) af[i] = *(const s16x8*)&As[wr * 64 + i * 16 + lr][lq * 8];
#pragma unroll
        for (int i = 0; i < 4; ++i) bfv[i] = *(const s16x8*)&Bs[wc * 64 + i * 16 + lr][lq * 8];
#pragma unroll
        for (int i = 0; i < 4; ++i)
#pragma unroll
            for (int j = 0; j < 4; ++j)
                acc[i][j] = __builtin_amdgcn_mfma_f32_16x16x32_bf16(af[i], bfv[j], acc[i][j], 0, 0, 0);
        __syncthreads();
    }

#pragma unroll
    for (int i = 0; i < 4; ++i) {
#pragma unroll
        for (int q = 0; q < 4; ++q) {
            const int grow = m0 + wr * 64 + i * 16 + lq * 4 + q;
            if (grow < N) {
#pragma unroll
                for (int j = 0; j < 4; ++j) {
                    const int col = wc * 64 + j * 16 + lr;
                    float v = acc[i][j][q] + bias[col];
                    if (LRELU) v = v > 0.f ? v : 0.01f * v;
                    out[(size_t)grow * 128 + col] = f2b(v);
                }
            }
        }
    }
}

// ---------------- final gather + classifier ----------------

__global__ __launch_bounds__(256) void k_out(const u16* __restrict__ h, const int* __restrict__ idx,
                                             const float* __restrict__ fc3w,
                                             const float* __restrict__ fc3b,
                                             float* __restrict__ out, int M) {
    int w = threadIdx.x >> 6;
    int lane = threadIdx.x & 63;
    int row = blockIdx.x * 4 + w;
    if (row >= M) return;
    int n = idx[row];
    u32 pair = *(const u32*)&h[(size_t)n * 128 + lane * 2];
    float v0 = __uint_as_float((pair & 0xFFFFu) << 16);
    float v1 = __uint_as_float((pair >> 16) << 16);
    float4 wv = *(const float4*)&fc3w[lane * 4];  // rows 2l, 2l+1 of [128,2]
    float s0 = v0 * wv.x + v1 * wv.z;
    float s1 = v0 * wv.y + v1 * wv.w;
    for (int off = 32; off >= 1; off >>= 1) {
        s0 += __shfl_xor(s0, off, 64);
        s1 += __shfl_xor(s1, off, 64);
    }
    if (lane == 0) {
        out[row * 2] = s0 + fc3b[0];
        out[row * 2 + 1] = s1 + fc3b[1];
    }
}

// ---------------- launch ----------------

extern "C" void kernel_launch(void* const* d_in, const int* in_sizes, int n_in,
                              void* d_out, int out_size, void* d_ws, size_t ws_size,
                              hipStream_t stream) {
    const float* vf    = (const float*)d_in[0];
    const float* tf    = (const float*)d_in[1];
    const float* fc1w  = (const float*)d_in[2];
    const float* fc1b  = (const float*)d_in[3];
    const float* fc2w  = (const float*)d_in[4];
    const float* fc2b  = (const float*)d_in[5];
    const float* reluw = (const float*)d_in[6];
    const float* relub = (const float*)d_in[7];
    const float* w1rel = (const float*)d_in[8];
    const float* w1root= (const float*)d_in[9];
    const float* b1    = (const float*)d_in[10];
    const float* w2rel = (const float*)d_in[11];
    const float* w2root= (const float*)d_in[12];
    const float* b2    = (const float*)d_in[13];
    const float* fc3w  = (const float*)d_in[14];
    const float* fc3b  = (const float*)d_in[15];
    const int* ei      = (const int*)d_in[16];
    const int* et      = (const int*)d_in[17];
    const int* idx     = (const int*)d_in[18];
    float* out = (float*)d_out;

    char* W = (char*)d_ws;
    // workspace layout (bytes)
    const size_t OFF_WTIN  = 0;         // 128*800*2 = 204800
    const size_t OFF_WT1   = 204800;    // 131072
    const size_t OFF_WT2   = 335872;    // 131072
    const size_t OFF_BCOMB = 466944;    // 512
    const size_t OFF_DEGN  = 467456;    // 200000
    const size_t OFF_CUR   = 667456;    // 200000
    const size_t OFF_DEGR  = 867456;    // 600000
    const size_t OFF_CNT   = 1467456;   // 4 (contiguous zero region DEGN..CNT = 250001 ints)
    const size_t OFF_BASE  = 1467712;   // 200000
    const size_t OFF_NORM  = 1667712;   // 600000
    const size_t OFF_ELIST = 2267712;   // 2400000
    const size_t OFF_A     = 4667712;   // 50000*384*2 = 38400000
    const size_t OFF_H0    = 43067712;  // 12800000
    const size_t OFF_H1    = 55867712;  // 12800000
    const size_t OFF_H2    = 68667712;  // 12800000 -> total 81467712

    u16* WTin   = (u16*)(W + OFF_WTIN);
    u16* WT1    = (u16*)(W + OFF_WT1);
    u16* WT2    = (u16*)(W + OFF_WT2);
    float* bcomb= (float*)(W + OFF_BCOMB);
    int* degn   = (int*)(W + OFF_DEGN);
    int* cur    = (int*)(W + OFF_CUR);
    int* degr   = (int*)(W + OFF_DEGR);
    int* cnt    = (int*)(W + OFF_CNT);
    int* base   = (int*)(W + OFF_BASE);
    float* normf= (float*)(W + OFF_NORM);
    int* elist  = (int*)(W + OFF_ELIST);
    u16* Abuf   = (u16*)(W + OFF_A);
    u16* h0     = (u16*)(W + OFF_H0);
    u16* h1     = (u16*)(W + OFF_H1);
    u16* h2     = (u16*)(W + OFF_H2);

    // 1. zero the atomic counters region (deg_node | cursor | deg_rel | counter)
    k_zero<<<(250001 + 255) / 256, 256, 0, stream>>>(degn, 250001);

    // 2. weight precompute
    k_win<<<800, 128, 0, stream>>>(fc1w, fc2w, reluw, WTin);
    k_bcomb<<<1, 128, 0, stream>>>(fc1b, fc2b, relub, reluw, bcomb);
    k_wrg<<<512, 128, 0, stream>>>(w1rel, w1root, WT1);
    k_wrg<<<512, 128, 0, stream>>>(w2rel, w2root, WT2);

    // 3. fused input GEMM: h0 = leakyrelu(tf@Wt + vf@Wv + bcomb)
    k_gemm<float, 24, 1, 16, true><<<391, 256, 0, stream>>>(
        tf, 768, vf, 16, WTin, 800, bcomb, h0, NN);

    // 4. CSR build (shared by both RGCN layers)
    k_hist<<<(NE + 255) / 256, 256, 0, stream>>>(ei, et, degn, degr);
    k_alloc<<<(NN + 255) / 256, 256, 0, stream>>>(degn, base, cnt);
    k_norm<<<(3 * NN + 255) / 256, 256, 0, stream>>>(degr, normf);
    k_fill<<<(NE + 255) / 256, 256, 0, stream>>>(ei, et, base, cur, elist);

    // 5. RGCN layer 1  (A2V=128: root-transform input has 128 valid cols — was the round-1 bug)
    k_agg<<<NN, 128, 0, stream>>>(h0, Abuf, elist, base, degn, normf);
    k_gemm<u16, 12, 4, 128, false><<<391, 256, 0, stream>>>(
        Abuf, 384, h0, 128, WT1, 512, b1, h1, NN);

    // 6. RGCN layer 2
    k_agg<<<NN, 128, 0, stream>>>(h1, Abuf, elist, base, degn, normf);
    k_gemm<u16, 12, 4, 128, false><<<391, 256, 0, stream>>>(
        Abuf, 384, h1, 128, WT2, 512, b2, h2, NN);

    // 7. classifier on gathered rows
    k_out<<<(10000 + 3) / 4, 256, 0, stream>>>(h2, idx, fc3w, fc3b, out, 10000);
}

// Round 3
// 312.917 us; speedup vs baseline: 1.1551x; 1.1551x over previous
//
#include <hip/hip_runtime.h>
#include <hip/hip_bf16.h>

typedef __attribute__((ext_vector_type(8))) short s16x8;
typedef __attribute__((ext_vector_type(4))) float f32x4;
typedef unsigned short u16;
typedef unsigned int u32;

constexpr int NN = 50000;
constexpr int NE = 600000;

__device__ inline u16 f2b(float x) {
    __hip_bfloat16 h = __float2bfloat16(x);   // RNE; compiler can fuse pairs to v_cvt_pk_bf16_f32
    return *(u16*)&h;
}
__device__ inline float b2f(u16 s) { return __uint_as_float(((u32)s) << 16); }

__device__ inline s16x8 pack8(float4 a, float4 b) {
    s16x8 r;
    r[0] = (short)f2b(a.x); r[1] = (short)f2b(a.y);
    r[2] = (short)f2b(a.z); r[3] = (short)f2b(a.w);
    r[4] = (short)f2b(b.x); r[5] = (short)f2b(b.y);
    r[6] = (short)f2b(b.z); r[7] = (short)f2b(b.w);
    return r;
}

// ---------------- misc small kernels ----------------

__global__ void k_zero(int* __restrict__ p, int n) {
    int i = blockIdx.x * 256 + threadIdx.x;
    if (i < n) p[i] = 0;
}

// WTin[c][k], k<768: (fc2_w @ relu_w_bot)^T ; 768..783: (fc1_w @ relu_w_top)^T ; 784..799: 0
__global__ void k_win(const float* __restrict__ fc1w, const float* __restrict__ fc2w,
                      const float* __restrict__ reluw, u16* __restrict__ WTin) {
    int c = threadIdx.x;         // 0..127 output col
    int k = blockIdx.x;          // 0..799
    float s = 0.f;
    if (k < 768) {
        for (int j = 0; j < 128; ++j) s += fc2w[k * 128 + j] * reluw[(128 + j) * 128 + c];
    } else if (k < 784) {
        int kk = k - 768;
        for (int j = 0; j < 128; ++j) s += fc1w[kk * 128 + j] * reluw[j * 128 + c];
    }
    WTin[c * 800 + k] = f2b(s);
}

__global__ void k_bcomb(const float* __restrict__ fc1b, const float* __restrict__ fc2b,
                        const float* __restrict__ relub, const float* __restrict__ reluw,
                        float* __restrict__ bcomb) {
    int c = threadIdx.x;
    float s = relub[c];
    for (int j = 0; j < 128; ++j) {
        s += fc1b[j] * reluw[j * 128 + c];
        s += fc2b[j] * reluw[(128 + j) * 128 + c];
    }
    bcomb[c] = s;
}

// WT[c][s] = stacked [wrel(3x128x128); wroot(128x128)] transposed, bf16
__global__ void k_wrg(const float* __restrict__ wrel, const float* __restrict__ wroot,
                      u16* __restrict__ WT) {
    int c = threadIdx.x;   // e index
    int s = blockIdx.x;    // 0..511 stacked row
    float v = (s < 384) ? wrel[(size_t)s * 128 + c] : wroot[(size_t)(s - 384) * 128 + c];
    WT[c * 512 + s] = f2b(v);
}

// ---------------- CSR build ----------------

__global__ void k_hist(const int* __restrict__ ei, const int* __restrict__ et,
                       int* __restrict__ deg_node, int* __restrict__ deg_rel) {
    int e = blockIdx.x * 256 + threadIdx.x;
    if (e >= NE) return;
    int dst = ei[NE + e];
    int r = et[e];
    atomicAdd(&deg_node[dst], 1);
    atomicAdd(&deg_rel[r * NN + dst], 1);
}

__global__ void k_alloc(const int* __restrict__ deg_node, int* __restrict__ baseoff,
                        int* __restrict__ counter) {
    int i = blockIdx.x * 256 + threadIdx.x;
    int lane = threadIdx.x & 63;
    int d = (i < NN) ? deg_node[i] : 0;
    int scan = d;
    for (int off = 1; off < 64; off <<= 1) {
        int t = __shfl_up(scan, off, 64);
        if (lane >= off) scan += t;
    }
    int total = __shfl(scan, 63, 64);
    int wbase = 0;
    if (lane == 63) wbase = atomicAdd(counter, total);
    wbase = __shfl(wbase, 63, 64);
    if (i < NN) baseoff[i] = wbase + scan - d;  // exclusive prefix within wave + global base
}

__global__ void k_norm(const int* __restrict__ deg_rel, float* __restrict__ normf) {
    int i = blockIdx.x * 256 + threadIdx.x;
    if (i < 3 * NN) normf[i] = 1.0f / (float)max(deg_rel[i], 1);
}

__global__ void k_fill(const int* __restrict__ ei, const int* __restrict__ et,
                       const int* __restrict__ baseoff, int* __restrict__ cursor,
                       int* __restrict__ elist) {
    int e = blockIdx.x * 256 + threadIdx.x;
    if (e >= NE) return;
    int dst = ei[NE + e];
    int src = ei[e];
    int r = et[e];
    int pos = atomicAdd(&cursor[dst], 1);
    elist[baseoff[dst] + pos] = src | (r << 20);
}

// ---------------- aggregation (gather over CSR): 1 wave per node, u32 loads ----------------

__global__ __launch_bounds__(64) void k_agg(const u16* __restrict__ x, u16* __restrict__ A,
                                            const int* __restrict__ elist,
                                            const int* __restrict__ baseoff,
                                            const int* __restrict__ deg_node,
                                            const float* __restrict__ normf) {
    int n = blockIdx.x;
    int lane = threadIdx.x;  // 0..63, handles feats 2*lane, 2*lane+1
    float a0x = 0.f, a0y = 0.f, a1x = 0.f, a1y = 0.f, a2x = 0.f, a2y = 0.f;
    int nb = deg_node[n];
    int b0 = baseoff[n];
    for (int i = 0; i < nb; ++i) {
        int p = elist[b0 + i];
        int src = p & 0xFFFFF;
        int r = p >> 20;
        u32 pair = *(const u32*)&x[(size_t)src * 128 + lane * 2];
        float vx = __uint_as_float((pair & 0xFFFFu) << 16);
        float vy = __uint_as_float((pair >> 16) << 16);
        if (r == 0)      { a0x += vx; a0y += vy; }
        else if (r == 1) { a1x += vx; a1y += vy; }
        else             { a2x += vx; a2y += vy; }
    }
    float n0 = normf[n], n1 = normf[NN + n], n2 = normf[2 * NN + n];
    u32* Ao = (u32*)&A[(size_t)n * 384];
    Ao[lane]        = (u32)f2b(a0x * n0) | ((u32)f2b(a0y * n0) << 16);
    Ao[64 + lane]   = (u32)f2b(a1x * n1) | ((u32)f2b(a1y * n1) << 16);
    Ao[128 + lane]  = (u32)f2b(a2x * n2) | ((u32)f2b(a2y * n2) << 16);
}

// ---------------- GEMM: [N, K1T*32 (+K2T*32)] x WT^T -> [N,128] bf16 ----------------
// M-tile 32 rows, 256 threads (4 waves, each owns a 32x32 output quadrant).
// A row = concat(A1 row (K1T tiles), A2 row (K2T tiles, first A2V cols valid, rest 0))
// WT is [128][ldwt] bf16 row-major (transposed weights). Epilogue: +bias, optional leaky-relu.

template <typename TA, int K1T, int K2T, int A2V, bool LRELU>
__global__ __launch_bounds__(256) void k_gemm(const TA* __restrict__ A1, int lda1,
                                              const TA* __restrict__ A2, int lda2,
                                              const u16* __restrict__ WT, int ldwt,
                                              const float* __restrict__ bias,
                                              u16* __restrict__ out, int N) {
    __shared__ u16 As[32][36];   // pitch 72B: stride 18 banks, gcd(18,32)=2 -> free 2-way
    __shared__ u16 Bs[128][36];  // Bs[col][k]
    const int tid = threadIdx.x;
    const int m0 = blockIdx.x * 32;
    const int w = tid >> 6, lane = tid & 63;
    const int lq = lane >> 4, lr = lane & 15;
    // A staging coords (tid < 128): row 0..31, kc in {0,8,16,24}
    const int arow = tid >> 2, akc = (tid & 3) * 8;
    // B staging coords (all 256): col 0..127, 16-elem half
    const int sr = tid >> 1, kcol = (tid & 1) * 16;
    constexpr int KT = K1T + K2T;

    f32x4 acc[2][2] = {};

    for (int kt = 0; kt < KT; ++kt) {
        // ---- stage A tile [32][32] (convert fp32->bf16 if needed) ----
        s16x8 a = {};
        if (tid < 128) {
            const int grow = m0 + arow;
            if (grow < N) {
                const TA* p = nullptr;
                if (kt < K1T) {
                    p = A1 + (size_t)grow * lda1 + kt * 32 + akc;
                } else {
                    int k2 = (kt - K1T) * 32 + akc;
                    if (k2 < A2V) p = A2 + (size_t)grow * lda2 + k2;
                }
                if (p) {
                    if constexpr (sizeof(TA) == 4) {
                        const float4* q = (const float4*)p;
                        float4 f0 = q[0], f1 = q[1];
                        a = pack8(f0, f1);
                    } else {
                        a = *(const s16x8*)p;
                    }
                }
            }
        }
        // ---- stage B tile: Bs[col][k] from WT[col][kt*32 + k] ----
        const u16* bp = WT + (size_t)sr * ldwt + kt * 32 + kcol;
        s16x8 blo = ((const s16x8*)bp)[0];
        s16x8 bhi = ((const s16x8*)bp)[1];

        if (tid < 128) *(s16x8*)&As[arow][akc] = a;
        *(s16x8*)&Bs[sr][kcol] = blo;
        *(s16x8*)&Bs[sr][kcol + 8] = bhi;
        __syncthreads();

        s16x8 af[2], bfv[2];
#pragma unroll
        for (int i = 0; i < 2; ++i) af[i] = *(const s16x8*)&As[i * 16 + lr][lq * 8];
#pragma unroll
        for (int j = 0; j < 2; ++j) bfv[j] = *(const s16x8*)&Bs[w * 32 + j * 16 + lr][lq * 8];
#pragma unroll
        for (int i = 0; i < 2; ++i)
#pragma unroll
            for (int j = 0; j < 2; ++j)
                acc[i][j] = __builtin_amdgcn_mfma_f32_16x16x32_bf16(af[i], bfv[j], acc[i][j], 0, 0, 0);
        __syncthreads();
    }

#pragma unroll
    for (int i = 0; i < 2; ++i) {
#pragma unroll
        for (int q = 0; q < 4; ++q) {
            const int grow = m0 + i * 16 + lq * 4 + q;
            if (grow < N) {
#pragma unroll
                for (int j = 0; j < 2; ++j) {
                    const int col = w * 32 + j * 16 + lr;
                    float v = acc[i][j][q] + bias[col];
                    if (LRELU) v = v > 0.f ? v : 0.01f * v;
                    out[(size_t)grow * 128 + col] = f2b(v);
                }
            }
        }
    }
}

// ---------------- final gather + classifier ----------------

__global__ __launch_bounds__(256) void k_out(const u16* __restrict__ h, const int* __restrict__ idx,
                                             const float* __restrict__ fc3w,
                                             const float* __restrict__ fc3b,
                                             float* __restrict__ out, int M) {
    int w = threadIdx.x >> 6;
    int lane = threadIdx.x & 63;
    int row = blockIdx.x * 4 + w;
    if (row >= M) return;
    int n = idx[row];
    u32 pair = *(const u32*)&h[(size_t)n * 128 + lane * 2];
    float v0 = __uint_as_float((pair & 0xFFFFu) << 16);
    float v1 = __uint_as_float((pair >> 16) << 16);
    float4 wv = *(const float4*)&fc3w[lane * 4];  // rows 2l, 2l+1 of [128,2]
    float s0 = v0 * wv.x + v1 * wv.z;
    float s1 = v0 * wv.y + v1 * wv.w;
    for (int off = 32; off >= 1; off >>= 1) {
        s0 += __shfl_xor(s0, off, 64);
        s1 += __shfl_xor(s1, off, 64);
    }
    if (lane == 0) {
        out[row * 2] = s0 + fc3b[0];
        out[row * 2 + 1] = s1 + fc3b[1];
    }
}

// ---------------- launch ----------------

extern "C" void kernel_launch(void* const* d_in, const int* in_sizes, int n_in,
                              void* d_out, int out_size, void* d_ws, size_t ws_size,
                              hipStream_t stream) {
    const float* vf    = (const float*)d_in[0];
    const float* tf    = (const float*)d_in[1];
    const float* fc1w  = (const float*)d_in[2];
    const float* fc1b  = (const float*)d_in[3];
    const float* fc2w  = (const float*)d_in[4];
    const float* fc2b  = (const float*)d_in[5];
    const float* reluw = (const float*)d_in[6];
    const float* relub = (const float*)d_in[7];
    const float* w1rel = (const float*)d_in[8];
    const float* w1root= (const float*)d_in[9];
    const float* b1    = (const float*)d_in[10];
    const float* w2rel = (const float*)d_in[11];
    const float* w2root= (const float*)d_in[12];
    const float* b2    = (const float*)d_in[13];
    const float* fc3w  = (const float*)d_in[14];
    const float* fc3b  = (const float*)d_in[15];
    const int* ei      = (const int*)d_in[16];
    const int* et      = (const int*)d_in[17];
    const int* idx     = (const int*)d_in[18];
    float* out = (float*)d_out;

    char* W = (char*)d_ws;
    // workspace layout (bytes)
    const size_t OFF_WTIN  = 0;         // 128*800*2 = 204800
    const size_t OFF_WT1   = 204800;    // 131072
    const size_t OFF_WT2   = 335872;    // 131072
    const size_t OFF_BCOMB = 466944;    // 512
    const size_t OFF_DEGN  = 467456;    // 200000
    const size_t OFF_CUR   = 667456;    // 200000
    const size_t OFF_DEGR  = 867456;    // 600000
    const size_t OFF_CNT   = 1467456;   // 4 (contiguous zero region DEGN..CNT = 250001 ints)
    const size_t OFF_BASE  = 1467712;   // 200000
    const size_t OFF_NORM  = 1667712;   // 600000
    const size_t OFF_ELIST = 2267712;   // 2400000
    const size_t OFF_A     = 4667712;   // 50000*384*2 = 38400000
    const size_t OFF_H0    = 43067712;  // 12800000
    const size_t OFF_H1    = 55867712;  // 12800000
    const size_t OFF_H2    = 68667712;  // 12800000 -> total 81467712

    u16* WTin   = (u16*)(W + OFF_WTIN);
    u16* WT1    = (u16*)(W + OFF_WT1);
    u16* WT2    = (u16*)(W + OFF_WT2);
    float* bcomb= (float*)(W + OFF_BCOMB);
    int* degn   = (int*)(W + OFF_DEGN);
    int* cur    = (int*)(W + OFF_CUR);
    int* degr   = (int*)(W + OFF_DEGR);
    int* cnt    = (int*)(W + OFF_CNT);
    int* base   = (int*)(W + OFF_BASE);
    float* normf= (float*)(W + OFF_NORM);
    int* elist  = (int*)(W + OFF_ELIST);
    u16* Abuf   = (u16*)(W + OFF_A);
    u16* h0     = (u16*)(W + OFF_H0);
    u16* h1     = (u16*)(W + OFF_H1);
    u16* h2     = (u16*)(W + OFF_H2);

    const int GRID_GEMM = (NN + 31) / 32;   // 1563 blocks -> ~6 blocks/CU

    // 1. zero the atomic counters region (deg_node | cursor | deg_rel | counter)
    k_zero<<<(250001 + 255) / 256, 256, 0, stream>>>(degn, 250001);

    // 2. weight precompute
    k_win<<<800, 128, 0, stream>>>(fc1w, fc2w, reluw, WTin);
    k_bcomb<<<1, 128, 0, stream>>>(fc1b, fc2b, relub, reluw, bcomb);
    k_wrg<<<512, 128, 0, stream>>>(w1rel, w1root, WT1);
    k_wrg<<<512, 128, 0, stream>>>(w2rel, w2root, WT2);

    // 3. fused input GEMM: h0 = leakyrelu(tf@Wt + vf@Wv + bcomb)
    k_gemm<float, 24, 1, 16, true><<<GRID_GEMM, 256, 0, stream>>>(
        tf, 768, vf, 16, WTin, 800, bcomb, h0, NN);

    // 4. CSR build (shared by both RGCN layers)
    k_hist<<<(NE + 255) / 256, 256, 0, stream>>>(ei, et, degn, degr);
    k_alloc<<<(NN + 255) / 256, 256, 0, stream>>>(degn, base, cnt);
    k_norm<<<(3 * NN + 255) / 256, 256, 0, stream>>>(degr, normf);
    k_fill<<<(NE + 255) / 256, 256, 0, stream>>>(ei, et, base, cur, elist);

    // 5. RGCN layer 1
    k_agg<<<NN, 64, 0, stream>>>(h0, Abuf, elist, base, degn, normf);
    k_gemm<u16, 12, 4, 128, false><<<GRID_GEMM, 256, 0, stream>>>(
        Abuf, 384, h0, 128, WT1, 512, b1, h1, NN);

    // 6. RGCN layer 2
    k_agg<<<NN, 64, 0, stream>>>(h1, Abuf, elist, base, degn, normf);
    k_gemm<u16, 12, 4, 128, false><<<GRID_GEMM, 256, 0, stream>>>(
        Abuf, 384, h1, 128, WT2, 512, b2, h2, NN);

    // 7. classifier on gathered rows
    k_out<<<(10000 + 3) / 4, 256, 0, stream>>>(h2, idx, fc3w, fc3b, out, 10000);
}